// Round 1
// baseline (521.886 us; speedup 1.0000x reference)
//
#include <hip/hip_runtime.h>
#include <math.h>

// Problem constants (fixed by the reference)
#define NN 131072
#define KK 1024
#define DD 64
#define GAMMA 0.99f
#define ALPHA 1e-9f
#define BETA 0.25f

// (1 - gamma) computed in double then rounded, matching the reference's
// Python-double 1.0-0.99 -> f32 cast.
__device__ __constant__ float OMG = (float)(1.0 - 0.99);

// ---------------------------------------------------------------------------
// Kernel 0: Esq[k] = sum_d E[k][d]^2
// ---------------------------------------------------------------------------
__global__ __launch_bounds__(256) void esq_kernel(const float* __restrict__ E,
                                                  float* __restrict__ Esq) {
    int lane = threadIdx.x & 63;
    int wave = threadIdx.x >> 6;
    int k = blockIdx.x * 4 + wave;
    float v = E[(size_t)k * DD + lane];
    float s = v * v;
    #pragma unroll
    for (int m = 32; m; m >>= 1) s += __shfl_xor(s, m, 64);
    if (lane == 0) Esq[k] = s;
}

// ---------------------------------------------------------------------------
// Kernel 1: fused distance + row-wise argmin.
// Block = 256 threads, 64 rows of X, loops over K in 64-col chunks.
// ---------------------------------------------------------------------------
#define BM 64
#define BN 64
#define LP 68   // padded leading dim (float4-aligned, breaks pow2 bank stride)

__global__ __launch_bounds__(256)
void vq_argmin(const float* __restrict__ X, const float* __restrict__ E,
               const float* __restrict__ Esq, float* __restrict__ argf,
               float* __restrict__ mind) {
    __shared__ float Xs[BM * LP];
    __shared__ float Es[BN * LP];
    __shared__ float xsq[BM];

    int tid = threadIdx.x;
    int tx = tid & 15, ty = tid >> 4;

    // stage X tile (64x64 floats, coalesced float4)
    const float* xsrc = X + (size_t)blockIdx.x * BM * DD;
    for (int i = tid; i < BM * DD / 4; i += 256) {
        float4 v = ((const float4*)xsrc)[i];
        int r = (i * 4) / DD, c = (i * 4) % DD;
        *(float4*)&Xs[r * LP + c] = v;
    }
    __syncthreads();
    if (tid < BM) {
        float s = 0.f;
        #pragma unroll
        for (int d = 0; d < DD; ++d) {
            float v = Xs[tid * LP + d];
            s = fmaf(v, v, s);
        }
        xsq[tid] = s;
    }

    float bestv[4];
    int besti[4];
    #pragma unroll
    for (int i = 0; i < 4; ++i) { bestv[i] = 3.402823466e38f; besti[i] = 0; }

    for (int chunk = 0; chunk < KK / BN; ++chunk) {
        __syncthreads();  // protect Es readers from previous chunk
        const float* esrc = E + (size_t)chunk * BN * DD;
        for (int i = tid; i < BN * DD / 4; i += 256) {
            float4 v = ((const float4*)esrc)[i];
            int r = (i * 4) / DD, c = (i * 4) % DD;
            *(float4*)&Es[r * LP + c] = v;
        }
        __syncthreads();

        float acc[4][4];
        #pragma unroll
        for (int i = 0; i < 4; ++i)
            #pragma unroll
            for (int j = 0; j < 4; ++j) acc[i][j] = 0.f;

        #pragma unroll
        for (int d = 0; d < DD; d += 4) {
            float4 a[4], b[4];
            #pragma unroll
            for (int i = 0; i < 4; ++i)
                a[i] = *(const float4*)&Xs[(ty * 4 + i) * LP + d];
            #pragma unroll
            for (int j = 0; j < 4; ++j)
                b[j] = *(const float4*)&Es[(tx * 4 + j) * LP + d];
            #pragma unroll
            for (int i = 0; i < 4; ++i)
                #pragma unroll
                for (int j = 0; j < 4; ++j) {
                    acc[i][j] = fmaf(a[i].x, b[j].x, acc[i][j]);
                    acc[i][j] = fmaf(a[i].y, b[j].y, acc[i][j]);
                    acc[i][j] = fmaf(a[i].z, b[j].z, acc[i][j]);
                    acc[i][j] = fmaf(a[i].w, b[j].w, acc[i][j]);
                }
        }

        int c0 = chunk * BN;
        float esq[4];
        #pragma unroll
        for (int j = 0; j < 4; ++j) esq[j] = Esq[c0 + tx * 4 + j];
        #pragma unroll
        for (int i = 0; i < 4; ++i) {
            float xq = xsq[ty * 4 + i];
            #pragma unroll
            for (int j = 0; j < 4; ++j) {
                float dist = fmaf(-2.f, acc[i][j], xq + esq[j]);
                int idx = c0 + tx * 4 + j;
                if (dist < bestv[i]) { bestv[i] = dist; besti[i] = idx; }
            }
        }
    }

    // cross-thread (16 col-threads per row) reduction via LDS (reuse Es)
    __syncthreads();
    float* redv = Es;                     // 64*17 floats
    int* redi = (int*)(Es + BM * 17);     // 64*17 ints
    #pragma unroll
    for (int i = 0; i < 4; ++i) {
        int row = ty * 4 + i;
        redv[row * 17 + tx] = bestv[i];
        redi[row * 17 + tx] = besti[i];
    }
    __syncthreads();
    if (tid < BM) {
        int row = tid;
        float bv = redv[row * 17];
        int bi = redi[row * 17];
        for (int t = 1; t < 16; ++t) {
            float v = redv[row * 17 + t];
            int ii = redi[row * 17 + t];
            if (v < bv || (v == bv && ii < bi)) { bv = v; bi = ii; }
        }
        size_t grow = (size_t)blockIdx.x * BM + row;
        argf[grow] = (float)bi;
        mind[grow] = bv;
    }
}

// ---------------------------------------------------------------------------
// Kernel 2: gather E[argmin], write Z, loss partials, scatter counts/sums.
// One wave per row; 4 rows per block.
// ---------------------------------------------------------------------------
__global__ __launch_bounds__(256)
void vq_gather(const float* __restrict__ X, const float* __restrict__ E,
               const float* __restrict__ argf, float* __restrict__ Z,
               float* __restrict__ counts, float* __restrict__ sums,
               float* __restrict__ loss_part) {
    __shared__ float wsum[4];
    int lane = threadIdx.x & 63;
    int wave = threadIdx.x >> 6;
    size_t row = (size_t)blockIdx.x * 4 + wave;
    int a = (int)argf[row];
    float x = X[row * DD + lane];
    float e = E[(size_t)a * DD + lane];
    Z[row * DD + lane] = x + (e - x);   // straight-through, same op order as ref
    float d = x - e;
    float s = d * d;
    #pragma unroll
    for (int m = 32; m; m >>= 1) s += __shfl_xor(s, m, 64);
    atomicAdd(&sums[a * DD + lane], x);
    if (lane == 0) {
        wsum[wave] = s;
        atomicAdd(&counts[a], 1.0f);
    }
    __syncthreads();
    if (threadIdx.x == 0) {
        float t = wsum[0] + wsum[1] + wsum[2] + wsum[3];
        atomicAdd(&loss_part[blockIdx.x & 1023], t);
    }
}

// ---------------------------------------------------------------------------
// Kernel 3: single block: cs (normalized cluster sizes) + loss finalize.
// ---------------------------------------------------------------------------
__global__ __launch_bounds__(1024)
void vq_cs(const float* __restrict__ cluster_sizes, const float* __restrict__ counts,
           const float* __restrict__ loss_part, float* __restrict__ out_cs,
           float* __restrict__ out_loss) {
    __shared__ float red[1024];
    int k = threadIdx.x;
    float csr = GAMMA * cluster_sizes[k] + OMG * counts[k];
    red[k] = csr;
    __syncthreads();
    for (int off = 512; off; off >>= 1) {
        if (k < off) red[k] += red[k + off];
        __syncthreads();
    }
    float total = red[0];
    __syncthreads();
    // second reduction: loss partials
    red[k] = loss_part[k];
    __syncthreads();
    for (int off = 512; off; off >>= 1) {
        if (k < off) red[k] += red[k + off];
        __syncthreads();
    }
    if (k == 0) out_loss[0] = BETA * (red[0] / (float)NN);

    float denom = 1.0f + (ALPHA * (float)KK) / total;
    float cs = (csr + ALPHA) / denom;
    out_cs[k] = cs;
}

// ---------------------------------------------------------------------------
// Kernel 4: ma = gamma*moving_avg + (1-gamma)*sums ; E_new = ma / cs
// ---------------------------------------------------------------------------
__global__ __launch_bounds__(256)
void vq_ema(const float* __restrict__ moving_avg, const float* __restrict__ sums,
            const float* __restrict__ cs, float* __restrict__ out_ma,
            float* __restrict__ out_enew) {
    int idx = blockIdx.x * 256 + threadIdx.x;
    int k = idx >> 6;
    float ma = GAMMA * moving_avg[idx] + OMG * sums[idx];
    out_ma[idx] = ma;
    out_enew[idx] = ma / cs[k];
}

// ---------------------------------------------------------------------------
extern "C" void kernel_launch(void* const* d_in, const int* in_sizes, int n_in,
                              void* d_out, int out_size, void* d_ws, size_t ws_size,
                              hipStream_t stream) {
    const float* X = (const float*)d_in[0];
    const float* E = (const float*)d_in[1];
    const float* cluster_sizes = (const float*)d_in[2];
    const float* moving_avg = (const float*)d_in[3];

    // Output layout (flat, return order):
    // Z[N*D], loss[1], argmins[N], min_dist[N], E_new[K*D], cs[K], ma[K*D]
    float* out = (float*)d_out;
    float* o_Z = out;
    float* o_loss = o_Z + (size_t)NN * DD;
    float* o_arg = o_loss + 1;
    float* o_mind = o_arg + NN;
    float* o_enew = o_mind + NN;
    float* o_cs = o_enew + (size_t)KK * DD;
    float* o_ma = o_cs + KK;

    // Workspace layout (floats): counts[K] | sums[K*D] | loss_part[1024] | Esq[K]
    float* ws = (float*)d_ws;
    float* counts = ws;
    float* sums = counts + KK;
    float* loss_part = sums + (size_t)KK * DD;
    float* Esq = loss_part + 1024;

    // zero the atomic accumulators (ws is poisoned 0xAA before every call)
    hipMemsetAsync(d_ws, 0, (KK + (size_t)KK * DD + 1024) * sizeof(float), stream);

    esq_kernel<<<KK / 4, 256, 0, stream>>>(E, Esq);
    vq_argmin<<<NN / BM, 256, 0, stream>>>(X, E, Esq, o_arg, o_mind);
    vq_gather<<<NN / 4, 256, 0, stream>>>(X, E, o_arg, o_Z, counts, sums, loss_part);
    vq_cs<<<1, 1024, 0, stream>>>(cluster_sizes, counts, loss_part, o_cs, o_loss);
    vq_ema<<<(KK * DD) / 256, 256, 0, stream>>>(moving_avg, sums, o_cs, o_ma, o_enew);
}

// Round 2
// 344.463 us; speedup vs baseline: 1.5151x; 1.5151x over previous
//
#include <hip/hip_runtime.h>
#include <math.h>

// Problem constants (fixed by the reference)
#define NN 131072
#define KK 1024
#define DD 64
#define GAMMA 0.99f
#define ALPHA 1e-9f
#define BETA 0.25f

__device__ __constant__ float OMG = (float)(1.0 - 0.99);

// ---------------------------------------------------------------------------
// Kernel 0: Esq[k] = sum_d E[k][d]^2
// ---------------------------------------------------------------------------
__global__ __launch_bounds__(256) void esq_kernel(const float* __restrict__ E,
                                                  float* __restrict__ Esq) {
    int lane = threadIdx.x & 63;
    int wave = threadIdx.x >> 6;
    int k = blockIdx.x * 4 + wave;
    float v = E[(size_t)k * DD + lane];
    float s = v * v;
    #pragma unroll
    for (int m = 32; m; m >>= 1) s += __shfl_xor(s, m, 64);
    if (lane == 0) Esq[k] = s;
}

// ---------------------------------------------------------------------------
// Kernel 1: fused distance + argmin + Z/loss/counts/sums epilogue.
// 128x128 tile, 256 threads, 8x8 micro-tile per thread.
// Micro-tile mapping: rows {ty+16i} (16-lane LDS broadcast reads),
// cols {tx+16j} (adjacent-lane stride LP -> conflict-free b128 reads).
// ---------------------------------------------------------------------------
#define BM 128
#define BN 128
#define TM 8
#define TN 8
#define LP 68   // padded leading dim

__global__ __launch_bounds__(256, 2)
void vq_main(const float* __restrict__ X, const float* __restrict__ E,
             const float* __restrict__ Esq, float* __restrict__ argf,
             float* __restrict__ mind, float* __restrict__ Z,
             float* __restrict__ counts, float* __restrict__ sums,
             float* __restrict__ loss_part) {
    __shared__ float Xs[BM * LP];     // 34816 B
    __shared__ float Es[BN * LP];     // 34816 B (reused as reduce scratch)
    __shared__ float xsq[BM];
    __shared__ float esqs[KK];        // 4 KB
    __shared__ int bidx[BM];

    int tid = threadIdx.x;
    int tx = tid & 15, ty = tid >> 4;

    // stage X tile (128x64 floats, coalesced float4)
    const float* xsrc = X + (size_t)blockIdx.x * BM * DD;
    #pragma unroll
    for (int it = 0; it < BM * DD / 4 / 256; ++it) {
        int i = it * 256 + tid;
        float4 v = ((const float4*)xsrc)[i];
        int r = (i * 4) / DD, c = (i * 4) % DD;
        *(float4*)&Xs[r * LP + c] = v;
    }
    // stage Esq (1024 floats)
    ((float4*)esqs)[tid] = ((const float4*)Esq)[tid];
    __syncthreads();

    // per-row |x|^2
    if (tid < BM) {
        float s = 0.f;
        #pragma unroll
        for (int d = 0; d < DD; ++d) {
            float v = Xs[tid * LP + d];
            s = fmaf(v, v, s);
        }
        xsq[tid] = s;
    }

    float bestv[TM];
    int besti[TM];
    #pragma unroll
    for (int i = 0; i < TM; ++i) { bestv[i] = 3.402823466e38f; besti[i] = 0; }

    for (int chunk = 0; chunk < KK / BN; ++chunk) {
        __syncthreads();  // previous chunk's readers done with Es
        const float* esrc = E + (size_t)chunk * BN * DD;
        #pragma unroll
        for (int it = 0; it < BN * DD / 4 / 256; ++it) {
            int i = it * 256 + tid;
            float4 v = ((const float4*)esrc)[i];
            int r = (i * 4) / DD, c = (i * 4) % DD;
            *(float4*)&Es[r * LP + c] = v;
        }
        __syncthreads();

        float acc[TM][TN];
        #pragma unroll
        for (int i = 0; i < TM; ++i)
            #pragma unroll
            for (int j = 0; j < TN; ++j) acc[i][j] = 0.f;

        #pragma unroll 2
        for (int d = 0; d < DD; d += 4) {
            float4 a[TM], b[TN];
            #pragma unroll
            for (int i = 0; i < TM; ++i)
                a[i] = *(const float4*)&Xs[(ty + 16 * i) * LP + d];
            #pragma unroll
            for (int j = 0; j < TN; ++j)
                b[j] = *(const float4*)&Es[(tx + 16 * j) * LP + d];
            #pragma unroll
            for (int i = 0; i < TM; ++i)
                #pragma unroll
                for (int j = 0; j < TN; ++j) {
                    acc[i][j] = fmaf(a[i].x, b[j].x, acc[i][j]);
                    acc[i][j] = fmaf(a[i].y, b[j].y, acc[i][j]);
                    acc[i][j] = fmaf(a[i].z, b[j].z, acc[i][j]);
                    acc[i][j] = fmaf(a[i].w, b[j].w, acc[i][j]);
                }
        }

        int c0 = chunk * BN;
        float esq[TN];
        #pragma unroll
        for (int j = 0; j < TN; ++j) esq[j] = esqs[c0 + tx + 16 * j];
        #pragma unroll
        for (int i = 0; i < TM; ++i) {
            float xq = xsq[ty + 16 * i];
            #pragma unroll
            for (int j = 0; j < TN; ++j) {
                float dist = fmaf(-2.f, acc[i][j], xq + esq[j]);
                int idx = c0 + tx + 16 * j;
                if (dist < bestv[i]) { bestv[i] = dist; besti[i] = idx; }
            }
        }
    }

    // cross-thread (16 tx per row) reduction via LDS (reuse Es)
    __syncthreads();
    float* redv = Es;                      // 128*17 floats
    int* redi = (int*)(Es + BM * 17);      // 128*17 ints
    #pragma unroll
    for (int i = 0; i < TM; ++i) {
        int row = ty + 16 * i;
        redv[row * 17 + tx] = bestv[i];
        redi[row * 17 + tx] = besti[i];
    }
    __syncthreads();
    if (tid < BM) {
        int row = tid;
        float bv = redv[row * 17];
        int bi = redi[row * 17];
        #pragma unroll
        for (int t = 1; t < 16; ++t) {
            float v = redv[row * 17 + t];
            int ii = redi[row * 17 + t];
            if (v < bv || (v == bv && ii < bi)) { bv = v; bi = ii; }
        }
        size_t grow = (size_t)blockIdx.x * BM + row;
        argf[grow] = (float)bi;
        mind[grow] = bv;
        bidx[row] = bi;
    }
    __syncthreads();

    // fused gather epilogue: Z, loss, counts, sums
    int lane = tid & 63;
    int wv = tid >> 6;
    float lsum = 0.f;
    #pragma unroll 2
    for (int it = 0; it < BM / 4; ++it) {
        int row = wv * (BM / 4) + it;
        int bi = bidx[row];                       // LDS broadcast
        float x = Xs[row * LP + lane];            // LDS broadcast-free read
        float e = E[(size_t)bi * DD + lane];      // L2-hot gather
        size_t grow = (size_t)blockIdx.x * BM + row;
        Z[grow * DD + lane] = x + (e - x);
        float d = x - e;
        lsum = fmaf(d, d, lsum);
        atomicAdd(&sums[bi * DD + lane], x);
        if (lane == 0) atomicAdd(&counts[bi], 1.0f);
    }
    #pragma unroll
    for (int m = 32; m; m >>= 1) lsum += __shfl_xor(lsum, m, 64);
    if (lane == 0)
        atomicAdd(&loss_part[(blockIdx.x * 4 + wv) & 1023], lsum);
}

// ---------------------------------------------------------------------------
// Kernel 3: single block: cs (normalized cluster sizes) + loss finalize.
// ---------------------------------------------------------------------------
__global__ __launch_bounds__(1024)
void vq_cs(const float* __restrict__ cluster_sizes, const float* __restrict__ counts,
           const float* __restrict__ loss_part, float* __restrict__ out_cs,
           float* __restrict__ out_loss) {
    __shared__ float red[1024];
    int k = threadIdx.x;
    float csr = GAMMA * cluster_sizes[k] + OMG * counts[k];
    red[k] = csr;
    __syncthreads();
    for (int off = 512; off; off >>= 1) {
        if (k < off) red[k] += red[k + off];
        __syncthreads();
    }
    float total = red[0];
    __syncthreads();
    red[k] = loss_part[k];
    __syncthreads();
    for (int off = 512; off; off >>= 1) {
        if (k < off) red[k] += red[k + off];
        __syncthreads();
    }
    if (k == 0) out_loss[0] = BETA * (red[0] / (float)NN);

    float denom = 1.0f + (ALPHA * (float)KK) / total;
    float cs = (csr + ALPHA) / denom;
    out_cs[k] = cs;
}

// ---------------------------------------------------------------------------
// Kernel 4: ma = gamma*moving_avg + (1-gamma)*sums ; E_new = ma / cs
// ---------------------------------------------------------------------------
__global__ __launch_bounds__(256)
void vq_ema(const float* __restrict__ moving_avg, const float* __restrict__ sums,
            const float* __restrict__ cs, float* __restrict__ out_ma,
            float* __restrict__ out_enew) {
    int idx = blockIdx.x * 256 + threadIdx.x;
    int k = idx >> 6;
    float ma = GAMMA * moving_avg[idx] + OMG * sums[idx];
    out_ma[idx] = ma;
    out_enew[idx] = ma / cs[k];
}

// ---------------------------------------------------------------------------
extern "C" void kernel_launch(void* const* d_in, const int* in_sizes, int n_in,
                              void* d_out, int out_size, void* d_ws, size_t ws_size,
                              hipStream_t stream) {
    const float* X = (const float*)d_in[0];
    const float* E = (const float*)d_in[1];
    const float* cluster_sizes = (const float*)d_in[2];
    const float* moving_avg = (const float*)d_in[3];

    // Output layout: Z[N*D], loss[1], argmins[N], min_dist[N],
    //                E_new[K*D], cs[K], ma[K*D]
    float* out = (float*)d_out;
    float* o_Z = out;
    float* o_loss = o_Z + (size_t)NN * DD;
    float* o_arg = o_loss + 1;
    float* o_mind = o_arg + NN;
    float* o_enew = o_mind + NN;
    float* o_cs = o_enew + (size_t)KK * DD;
    float* o_ma = o_cs + KK;

    // Workspace: counts[K] | sums[K*D] | loss_part[1024] | Esq[K]
    float* ws = (float*)d_ws;
    float* counts = ws;
    float* sums = counts + KK;
    float* loss_part = sums + (size_t)KK * DD;
    float* Esq = loss_part + 1024;

    hipMemsetAsync(d_ws, 0, (KK + (size_t)KK * DD + 1024) * sizeof(float), stream);

    esq_kernel<<<KK / 4, 256, 0, stream>>>(E, Esq);
    vq_main<<<NN / BM, 256, 0, stream>>>(X, E, Esq, o_arg, o_mind, o_Z,
                                         counts, sums, loss_part);
    vq_cs<<<1, 1024, 0, stream>>>(cluster_sizes, counts, loss_part, o_cs, o_loss);
    vq_ema<<<(KK * DD) / 256, 256, 0, stream>>>(moving_avg, sums, o_cs, o_ma, o_enew);
}

// Round 3
// 230.998 us; speedup vs baseline: 2.2593x; 1.4912x over previous
//
#include <hip/hip_runtime.h>
#include <math.h>

// Problem constants (fixed by the reference)
#define NN 131072
#define KK 1024
#define DD 64
#define GAMMA 0.99f
#define ALPHA 1e-9f
#define BETA 0.25f

typedef float f32x4 __attribute__((ext_vector_type(4)));
typedef short bf16x8 __attribute__((ext_vector_type(8)));

__device__ __constant__ float OMG = (float)(1.0 - 0.99);

// split fp32 -> hi (truncated bf16) + lo (RNE bf16 of residual); x ~= hi+lo to ~2^-17 rel
__device__ __forceinline__ void split_bf16(float v, unsigned short& h, unsigned short& l) {
    unsigned int b = __float_as_uint(v);
    unsigned int hb = b & 0xFFFF0000u;
    h = (unsigned short)(hb >> 16);
    float r = v - __uint_as_float(hb);
    unsigned int lb = __float_as_uint(r);
    lb += 0x7FFFu + ((lb >> 16) & 1u);
    l = (unsigned short)(lb >> 16);
}

// ---------------------------------------------------------------------------
// Prep: build E B-fragments in MFMA layout (hi/lo split) + esq.
// Frag (nt, ks, s): 1024 B; lane l holds E[nt*16 + (l&15)][ks*32 + (l>>4)*8 + j].
// float4 index = frag_id*64 + l, frag_id = nt*4 + ks*2 + s.
// One wave per n-tile (64 blocks x 64 threads).
// ---------------------------------------------------------------------------
__global__ __launch_bounds__(64)
void vq_prep(const float* __restrict__ E, float4* __restrict__ Efrag,
             float* __restrict__ esq) {
    int nt = blockIdx.x;
    int l = threadIdx.x;
    int n = nt * 16 + (l & 15);
    int kb = (l >> 4) * 8;
    float ss = 0.f;
    #pragma unroll
    for (int ks = 0; ks < 2; ++ks) {
        const float4* xp = (const float4*)(E + (size_t)n * DD + ks * 32 + kb);
        float4 a = xp[0], b = xp[1];
        float v[8] = {a.x, a.y, a.z, a.w, b.x, b.y, b.z, b.w};
        union { float4 f; unsigned short u[8]; } H, L;
        #pragma unroll
        for (int j = 0; j < 8; ++j) {
            unsigned short hh, ll;
            split_bf16(v[j], hh, ll);
            H.u[j] = hh; L.u[j] = ll;
            ss = fmaf(v[j], v[j], ss);
        }
        int fid = nt * 4 + ks * 2;
        Efrag[(size_t)(fid + 0) * 64 + l] = H.f;
        Efrag[(size_t)(fid + 1) * 64 + l] = L.f;
    }
    // esq: lanes l, l^16, l^32, l^48 share row n
    ss += __shfl_xor(ss, 16, 64);
    ss += __shfl_xor(ss, 32, 64);
    if (l < 16) esq[nt * 16 + l] = ss;
}

// ---------------------------------------------------------------------------
// Main: split-bf16 MFMA distance GEMM + argmin + gather epilogue.
// Block = 256 threads (4 waves), BM = 128 rows. Wave w: row-group rg=w&1
// (64 rows = 4 m-tiles, A frags register-resident), col-group cg=w>>1
// (512 cols = 32 n-tiles, B frags streamed from L2). No LDS in the K-sweep.
// score = esq[n] - 2*x.e  (xsq constant per row -> dropped from argmin).
// ---------------------------------------------------------------------------
#define BM 128

__global__ __launch_bounds__(256, 2)
void vq_main(const float* __restrict__ X, const float* __restrict__ E,
             const float4* __restrict__ Efrag, const float* __restrict__ esq,
             float* __restrict__ argf, float* __restrict__ mind,
             float* __restrict__ Z, float* __restrict__ counts,
             float* __restrict__ sums, float* __restrict__ loss_part) {
    __shared__ float redv[256];
    __shared__ int redi[256];
    __shared__ int bidx[128];

    int tid = threadIdx.x;
    int lane = tid & 63, w = tid >> 6;
    int rg = w & 1, cg = w >> 1;
    int lc = lane & 15, lq = lane >> 4;

    size_t R0 = (size_t)blockIdx.x * BM + rg * 64;

    // A fragments: 4 m-tiles x 2 k-steps, hi+lo (64 VGPRs)
    bf16x8 ah[4][2], al[4][2];
    #pragma unroll
    for (int mt = 0; mt < 4; ++mt) {
        #pragma unroll
        for (int ks = 0; ks < 2; ++ks) {
            const float4* xp =
                (const float4*)(X + (R0 + mt * 16 + lc) * DD + ks * 32 + lq * 8);
            float4 x0 = xp[0], x1 = xp[1];
            float v[8] = {x0.x, x0.y, x0.z, x0.w, x1.x, x1.y, x1.z, x1.w};
            union { bf16x8 s; unsigned short u[8]; } H, L;
            #pragma unroll
            for (int j = 0; j < 8; ++j) {
                unsigned short hh, ll;
                split_bf16(v[j], hh, ll);
                H.u[j] = hh; L.u[j] = ll;
            }
            ah[mt][ks] = H.s;
            al[mt][ks] = L.s;
        }
    }

    float bestv[4][4];
    int besti[4][4];
    #pragma unroll
    for (int mt = 0; mt < 4; ++mt)
        #pragma unroll
        for (int r = 0; r < 4; ++r) { bestv[mt][r] = 3.402823466e38f; besti[mt][r] = 0; }

    const float4* bp = Efrag + (size_t)(cg * 32) * 256 + lane;
    const float* ep = esq + cg * 512 + lc;

    // software prefetch depth 1
    float4 nb0 = bp[0], nb1 = bp[64], nb2 = bp[128], nb3 = bp[192];
    float en = ep[0];

    for (int nt = 0; nt < 32; ++nt) {
        float4 cb0 = nb0, cb1 = nb1, cb2 = nb2, cb3 = nb3;
        float ec = en;
        if (nt < 31) {
            const float4* q = bp + (size_t)(nt + 1) * 256;
            nb0 = q[0]; nb1 = q[64]; nb2 = q[128]; nb3 = q[192];
            en = ep[(nt + 1) * 16];
        }
        union { float4 f; bf16x8 s; } u0, u1, u2, u3;
        u0.f = cb0; u1.f = cb1; u2.f = cb2; u3.f = cb3;
        bf16x8 bh0 = u0.s, bl0 = u1.s, bh1 = u2.s, bl1 = u3.s;

        f32x4 acc[4];
        #pragma unroll
        for (int mt = 0; mt < 4; ++mt) acc[mt] = (f32x4){0.f, 0.f, 0.f, 0.f};

        // 3-pass split product: hh (k0,k1), hl, lh
        #pragma unroll
        for (int mt = 0; mt < 4; ++mt)
            acc[mt] = __builtin_amdgcn_mfma_f32_16x16x32_bf16(ah[mt][0], bh0, acc[mt], 0, 0, 0);
        #pragma unroll
        for (int mt = 0; mt < 4; ++mt)
            acc[mt] = __builtin_amdgcn_mfma_f32_16x16x32_bf16(ah[mt][1], bh1, acc[mt], 0, 0, 0);
        #pragma unroll
        for (int mt = 0; mt < 4; ++mt)
            acc[mt] = __builtin_amdgcn_mfma_f32_16x16x32_bf16(ah[mt][0], bl0, acc[mt], 0, 0, 0);
        #pragma unroll
        for (int mt = 0; mt < 4; ++mt)
            acc[mt] = __builtin_amdgcn_mfma_f32_16x16x32_bf16(ah[mt][1], bl1, acc[mt], 0, 0, 0);
        #pragma unroll
        for (int mt = 0; mt < 4; ++mt)
            acc[mt] = __builtin_amdgcn_mfma_f32_16x16x32_bf16(al[mt][0], bh0, acc[mt], 0, 0, 0);
        #pragma unroll
        for (int mt = 0; mt < 4; ++mt)
            acc[mt] = __builtin_amdgcn_mfma_f32_16x16x32_bf16(al[mt][1], bh1, acc[mt], 0, 0, 0);

        int n = cg * 512 + nt * 16 + lc;
        #pragma unroll
        for (int mt = 0; mt < 4; ++mt) {
            #pragma unroll
            for (int r = 0; r < 4; ++r) {
                float sc = fmaf(-2.f, acc[mt][r], ec);
                if (sc < bestv[mt][r]) { bestv[mt][r] = sc; besti[mt][r] = n; }
            }
        }
    }

    // reduce across the 16 lanes holding one row (C layout: col=lane&15)
    #pragma unroll
    for (int off = 1; off <= 8; off <<= 1) {
        #pragma unroll
        for (int mt = 0; mt < 4; ++mt) {
            #pragma unroll
            for (int r = 0; r < 4; ++r) {
                float ov = __shfl_xor(bestv[mt][r], off, 64);
                int oi = __shfl_xor(besti[mt][r], off, 64);
                if (ov < bestv[mt][r] || (ov == bestv[mt][r] && oi < besti[mt][r])) {
                    bestv[mt][r] = ov; besti[mt][r] = oi;
                }
            }
        }
    }
    if (lc == 0) {
        #pragma unroll
        for (int mt = 0; mt < 4; ++mt)
            #pragma unroll
            for (int r = 0; r < 4; ++r) {
                int row = rg * 64 + mt * 16 + lq * 4 + r;
                redv[row * 2 + cg] = bestv[mt][r];
                redi[row * 2 + cg] = besti[mt][r];
            }
    }
    __syncthreads();
    if (tid < 128) {
        float v0 = redv[tid * 2], v1 = redv[tid * 2 + 1];
        int i0 = redi[tid * 2], i1 = redi[tid * 2 + 1];
        bidx[tid] = (v1 < v0 || (v1 == v0 && i1 < i0)) ? i1 : i0;
    }
    __syncthreads();

    // gather epilogue: Z, exact min_dist, loss, counts, sums
    float lsum = 0.f;
    for (int it = 0; it < 32; ++it) {
        int row = w * 32 + it;
        int bi = bidx[row];
        size_t grow = (size_t)blockIdx.x * BM + row;
        float x = X[grow * DD + lane];
        float e = E[(size_t)bi * DD + lane];
        Z[grow * DD + lane] = x + (e - x);
        float d = x - e;
        float s = d * d;
        #pragma unroll
        for (int m = 32; m; m >>= 1) s += __shfl_xor(s, m, 64);
        atomicAdd(&sums[bi * DD + lane], x);
        if (lane == 0) {
            atomicAdd(&counts[bi], 1.0f);
            argf[grow] = (float)bi;
            mind[grow] = s;   // exact fp32 sum((x-e)^2)
        }
        lsum += s;
    }
    if (lane == 0) atomicAdd(&loss_part[(blockIdx.x * 4 + w) & 1023], lsum);
}

// ---------------------------------------------------------------------------
// cs (normalized cluster sizes) + loss finalize — single block.
// ---------------------------------------------------------------------------
__global__ __launch_bounds__(1024)
void vq_cs(const float* __restrict__ cluster_sizes, const float* __restrict__ counts,
           const float* __restrict__ loss_part, float* __restrict__ out_cs,
           float* __restrict__ out_loss) {
    __shared__ float red[1024];
    int k = threadIdx.x;
    float csr = GAMMA * cluster_sizes[k] + OMG * counts[k];
    red[k] = csr;
    __syncthreads();
    for (int off = 512; off; off >>= 1) {
        if (k < off) red[k] += red[k + off];
        __syncthreads();
    }
    float total = red[0];
    __syncthreads();
    red[k] = loss_part[k];
    __syncthreads();
    for (int off = 512; off; off >>= 1) {
        if (k < off) red[k] += red[k + off];
        __syncthreads();
    }
    if (k == 0) out_loss[0] = BETA * (red[0] / (float)NN);

    float denom = 1.0f + (ALPHA * (float)KK) / total;
    out_cs[k] = (csr + ALPHA) / denom;
}

// ---------------------------------------------------------------------------
// ma = gamma*moving_avg + (1-gamma)*sums ; E_new = ma / cs
// ---------------------------------------------------------------------------
__global__ __launch_bounds__(256)
void vq_ema(const float* __restrict__ moving_avg, const float* __restrict__ sums,
            const float* __restrict__ cs, float* __restrict__ out_ma,
            float* __restrict__ out_enew) {
    int idx = blockIdx.x * 256 + threadIdx.x;
    int k = idx >> 6;
    float ma = GAMMA * moving_avg[idx] + OMG * sums[idx];
    out_ma[idx] = ma;
    out_enew[idx] = ma / cs[k];
}

// ---------------------------------------------------------------------------
extern "C" void kernel_launch(void* const* d_in, const int* in_sizes, int n_in,
                              void* d_out, int out_size, void* d_ws, size_t ws_size,
                              hipStream_t stream) {
    const float* X = (const float*)d_in[0];
    const float* E = (const float*)d_in[1];
    const float* cluster_sizes = (const float*)d_in[2];
    const float* moving_avg = (const float*)d_in[3];

    // Output layout: Z[N*D], loss[1], argmins[N], min_dist[N],
    //                E_new[K*D], cs[K], ma[K*D]
    float* out = (float*)d_out;
    float* o_Z = out;
    float* o_loss = o_Z + (size_t)NN * DD;
    float* o_arg = o_loss + 1;
    float* o_mind = o_arg + NN;
    float* o_enew = o_mind + NN;
    float* o_cs = o_enew + (size_t)KK * DD;
    float* o_ma = o_cs + KK;

    // Workspace: counts[1024] | sums[65536] | loss_part[1024] | esq[1024] | Efrag[65536 f]
    float* ws = (float*)d_ws;
    float* counts = ws;
    float* sums = counts + KK;
    float* loss_part = sums + (size_t)KK * DD;
    float* esq = loss_part + 1024;
    float4* Efrag = (float4*)(esq + KK);

    hipMemsetAsync(d_ws, 0, (KK + (size_t)KK * DD + 1024) * sizeof(float), stream);

    vq_prep<<<KK / 16, 64, 0, stream>>>(E, Efrag, esq);
    vq_main<<<NN / BM, 256, 0, stream>>>(X, E, Efrag, esq, o_arg, o_mind, o_Z,
                                         counts, sums, loss_part);
    vq_cs<<<1, 1024, 0, stream>>>(cluster_sizes, counts, loss_part, o_cs, o_loss);
    vq_ema<<<(KK * DD) / 256, 256, 0, stream>>>(moving_avg, sums, o_cs, o_ma, o_enew);
}